// Round 1
// baseline (1145.313 us; speedup 1.0000x reference)
//
#include <hip/hip_runtime.h>

typedef __bf16 bf16_t;
typedef bf16_t bf16x8 __attribute__((ext_vector_type(8)));
typedef float floatx4 __attribute__((ext_vector_type(4)));

#define NB 2
#define NL 1024
#define NCA 512
#define NCS 384
#define NCZ 64
#define NH 16
#define ND 32
#define NT (NB*NL)

static __device__ __forceinline__ float bflo(unsigned int w){ union{unsigned int i; float f;} x; x.i = w<<16; return x.f; }
static __device__ __forceinline__ float bfhi(unsigned int w){ union{unsigned int i; float f;} x; x.i = w & 0xffff0000u; return x.f; }
static __device__ __forceinline__ void unpack8(uint4 u, float* f){
    f[0]=bflo(u.x); f[1]=bfhi(u.x); f[2]=bflo(u.y); f[3]=bfhi(u.y);
    f[4]=bflo(u.z); f[5]=bfhi(u.z); f[6]=bflo(u.w); f[7]=bfhi(u.w);
}
static __device__ __forceinline__ bf16_t f2b(float f){ return (bf16_t)f; }
static __device__ __forceinline__ float sigmoidf_(float x){ return 1.f/(1.f + __expf(-x)); }

// ---------------------------------------------------------------------------
// prep: convert weights to bf16 (concatenated), build scaled wz + wsum + bcat
// ---------------------------------------------------------------------------
__global__ __launch_bounds__(256) void prep_kernel(
    const float* __restrict__ aws, const float* __restrict__ awnb,
    const float* __restrict__ wlast,
    const float* __restrict__ wq, const float* __restrict__ wk,
    const float* __restrict__ wv, const float* __restrict__ wg,
    const float* __restrict__ wo, const float* __restrict__ s,
    const float* __restrict__ wz, const float* __restrict__ lnz,
    const float* __restrict__ pbq, const float* __restrict__ pbk,
    const float* __restrict__ pbv, const float* __restrict__ pbg,
    bf16_t* __restrict__ Wada, bf16_t* __restrict__ Wlast,
    bf16_t* __restrict__ Wqkvg, bf16_t* __restrict__ Wo, bf16_t* __restrict__ sbf,
    float* __restrict__ wzs, float* __restrict__ wsum, float* __restrict__ bcat)
{
    int seg = blockIdx.y, bx = blockIdx.x, tid = threadIdx.x;
    if (seg < 9) {
        const float* src; bf16_t* dst; int nelem;
        switch (seg) {
            case 0: src=aws;  dst=Wada;          nelem=196608; break;
            case 1: src=awnb; dst=Wada+196608;   nelem=196608; break;
            case 2: src=wlast;dst=Wlast;         nelem=196608; break;
            case 3: src=wq;   dst=Wqkvg;         nelem=262144; break;
            case 4: src=wk;   dst=Wqkvg+262144;  nelem=262144; break;
            case 5: src=wv;   dst=Wqkvg+524288;  nelem=262144; break;
            case 6: src=wg;   dst=Wqkvg+786432;  nelem=262144; break;
            case 7: src=wo;   dst=Wo;            nelem=262144; break;
            default: src=s;   dst=sbf;           nelem=786432; break;
        }
        int base = bx * 1024;
        if (base >= nelem) return;
        #pragma unroll
        for (int i = 0; i < 4; i++) {
            int e = base + tid + i*256;
            if (e < nelem) dst[e] = f2b(src[e]);
        }
    } else if (seg == 9) {
        if (bx) return;
        #pragma unroll
        for (int i = 0; i < 4; i++) {
            int e = tid + i*256;           // 1024 = 16*64
            wzs[e] = wz[e] * lnz[e & 63];
        }
        __syncthreads();
        if (tid < 16) {
            float sum = 0.f;
            for (int c = 0; c < 64; c++) sum += wzs[tid*64 + c];
            wsum[tid] = sum;
        }
    } else {
        if (bx >= 2) return;
        #pragma unroll
        for (int i = 0; i < 4; i++) {
            int e = bx*1024 + tid + i*256;  // 2048
            float v = (e < 512) ? pbq[e] : (e < 1024) ? pbk[e-512]
                     : (e < 1536) ? pbv[e-1024] : pbg[e-1536];
            bcat[e] = v;
        }
    }
}

// ---------------------------------------------------------------------------
// LN of s (scaled, ->bf16) + mean/rstd stats of a.  One block per token.
// ---------------------------------------------------------------------------
__global__ __launch_bounds__(256) void ln_kernel(
    const float* __restrict__ s, const float* __restrict__ a,
    const float* __restrict__ lnscale,
    bf16_t* __restrict__ slnbf, float* __restrict__ astats)
{
    __shared__ float2 red[256];
    int t = blockIdx.x, tid = threadIdx.x;
    const float* sp = s + (size_t)t*NCS;
    float v0 = sp[tid];
    float v1 = (tid < 128) ? sp[256 + tid] : 0.f;
    float s1 = v0 + v1, s2 = v0*v0 + v1*v1;
    red[tid] = make_float2(s1, s2);
    __syncthreads();
    for (int off = 128; off; off >>= 1) {
        if (tid < off) { red[tid].x += red[tid+off].x; red[tid].y += red[tid+off].y; }
        __syncthreads();
    }
    float mean = red[0].x * (1.f/NCS);
    float var  = red[0].y * (1.f/NCS) - mean*mean;
    float rstd = rsqrtf(var + 1e-5f);
    slnbf[(size_t)t*NCS + tid] = f2b((v0 - mean)*rstd*lnscale[tid]);
    if (tid < 128) slnbf[(size_t)t*NCS + 256 + tid] = f2b((v1 - mean)*rstd*lnscale[256 + tid]);
    // a stats
    const float* ap = a + (size_t)t*NCA;
    float w0 = ap[tid], w1 = ap[256 + tid];
    float t1 = w0 + w1, t2 = w0*w0 + w1*w1;
    __syncthreads();
    red[tid] = make_float2(t1, t2);
    __syncthreads();
    for (int off = 128; off; off >>= 1) {
        if (tid < off) { red[tid].x += red[tid+off].x; red[tid].y += red[tid+off].y; }
        __syncthreads();
    }
    if (tid == 0) {
        float am = red[0].x * (1.f/NCA);
        float av = red[0].y * (1.f/NCA) - am*am;
        astats[2*t]   = am;
        astats[2*t+1] = rsqrtf(av + 1e-5f);
    }
}

// ---------------------------------------------------------------------------
// bf16 MFMA GEMM: C[M,N] = X[M,K] @ W[N,K]^T (+epilogue)
// MODE 0: store fp32 (no bias)
// MODE 1: +bias, sigmoid for n>=sig_start, store bf16
// MODE 2: +bias, *gate(bf16)[m,n], *mask[m], store fp32
// ---------------------------------------------------------------------------
template<int MODE>
__global__ __launch_bounds__(256) void gemm_kernel(
    const bf16_t* __restrict__ X, const bf16_t* __restrict__ W,
    const float* __restrict__ bias, int M, int N, int K, int sig_start,
    const bf16_t* __restrict__ gate, const int* __restrict__ mask,
    float* __restrict__ outF, bf16_t* __restrict__ outB)
{
    __shared__ __align__(16) bf16_t A_lds[64*40];
    __shared__ __align__(16) bf16_t B_lds[64*40];
    int tid = threadIdx.x;
    int lane = tid & 63, wave = tid >> 6;
    int l15 = lane & 15, quad = lane >> 4;
    int n0 = blockIdx.x * 64, m0 = blockIdx.y * 64;
    int lrow = tid >> 2, lchunk = tid & 3;
    const uint4* pX = (const uint4*)X;
    const uint4* pW = (const uint4*)W;
    floatx4 acc[4];
    #pragma unroll
    for (int i = 0; i < 4; i++) acc[i] = (floatx4){0.f,0.f,0.f,0.f};

    for (int k0 = 0; k0 < K; k0 += 32) {
        __syncthreads();
        *(uint4*)&A_lds[lrow*40 + lchunk*8] = pX[(((size_t)(m0+lrow))*K + k0 + lchunk*8) >> 3];
        *(uint4*)&B_lds[lrow*40 + lchunk*8] = pW[(((size_t)(n0+lrow))*K + k0 + lchunk*8) >> 3];
        __syncthreads();
        bf16x8 af = *(const bf16x8*)&A_lds[(wave*16 + l15)*40 + quad*8];
        #pragma unroll
        for (int ct = 0; ct < 4; ct++) {
            bf16x8 bfv = *(const bf16x8*)&B_lds[(ct*16 + l15)*40 + quad*8];
            acc[ct] = __builtin_amdgcn_mfma_f32_16x16x32_bf16(af, bfv, acc[ct], 0, 0, 0);
        }
    }
    #pragma unroll
    for (int ct = 0; ct < 4; ct++) {
        #pragma unroll
        for (int r = 0; r < 4; r++) {
            int m = m0 + wave*16 + quad*4 + r;
            int n = n0 + ct*16 + l15;
            float v = acc[ct][r];
            if (MODE == 0) {
                outF[(size_t)m*N + n] = v;
            } else if (MODE == 1) {
                v += bias[n];
                if (n >= sig_start) v = sigmoidf_(v);
                outB[(size_t)m*N + n] = f2b(v);
            } else {
                v += bias[n];
                v *= (float)gate[(size_t)m*N + n];
                v *= (mask[m] != 0) ? 1.f : 0.f;
                outF[(size_t)m*N + n] = v;
            }
        }
    }
}

// ---------------------------------------------------------------------------
// a_norm = sigmoid(ada_s + b) * (a-mean)*rstd + ada_nb   -> bf16
// ---------------------------------------------------------------------------
__global__ __launch_bounds__(256) void anorm_kernel(
    const float* __restrict__ ada_out, const float* __restrict__ ada_b,
    const float* __restrict__ a, const float* __restrict__ stats,
    bf16_t* __restrict__ anorm)
{
    int e = blockIdx.x * 1024 + threadIdx.x;
    #pragma unroll
    for (int i = 0; i < 4; i++, e += 256) {
        int t = e >> 9, c = e & 511;
        float x = ada_out[(size_t)t*1024 + c] + ada_b[c];
        float sig = sigmoidf_(x);
        float aln = (a[e] - stats[2*t]) * stats[2*t+1];
        anorm[e] = f2b(sig*aln + ada_out[(size_t)t*1024 + 512 + c]);
    }
}

// ---------------------------------------------------------------------------
// z -> pair bias:  bias[b,h,q,k] = LN(z[b,q,k,:], ln_z_scale) @ wz[h,:]
// wzs = wz*scale prefolded; bias_h = (sum(z*wzs_h) - mean*sum(wzs_h)) * rstd
// ---------------------------------------------------------------------------
__global__ __launch_bounds__(128) void biasz_kernel(
    const float* __restrict__ z, const float* __restrict__ wzs,
    const float* __restrict__ wsum, bf16_t* __restrict__ bias)
{
    __shared__ float zt[128*65];
    __shared__ float wsh[16*64 + 16];
    int tid = threadIdx.x;
    for (int i = tid; i < 16*64 + 16; i += 128)
        wsh[i] = (i < 1024) ? wzs[i] : wsum[i - 1024];
    size_t row0 = (size_t)blockIdx.x * 128;
    const float4* pz = (const float4*)(z + row0*64);
    #pragma unroll
    for (int i = 0; i < 16; i++) {
        int f4 = tid + i*128;
        float4 v = pz[f4];
        int r = f4 >> 4, c = (f4 & 15) << 2;
        zt[r*65 + c] = v.x; zt[r*65 + c + 1] = v.y; zt[r*65 + c + 2] = v.z; zt[r*65 + c + 3] = v.w;
    }
    __syncthreads();
    float zr[64];
    float s1 = 0.f, s2 = 0.f;
    #pragma unroll
    for (int c = 0; c < 64; c++) {
        float v = zt[tid*65 + c];
        zr[c] = v; s1 += v; s2 += v*v;
    }
    float mean = s1 * (1.f/64.f);
    float var  = s2 * (1.f/64.f) - mean*mean;
    float rstd = rsqrtf(var + 1e-5f);
    float acc[16];
    #pragma unroll
    for (int h = 0; h < 16; h++) acc[h] = 0.f;
    #pragma unroll
    for (int c = 0; c < 64; c++) {
        float v = zr[c];
        #pragma unroll
        for (int h = 0; h < 16; h++) acc[h] += v * wsh[h*64 + c];
    }
    size_t row = row0 + tid;
    size_t b = row >> 20, q = (row >> 10) & 1023, k = row & 1023;
    #pragma unroll
    for (int h = 0; h < 16; h++) {
        float bv = (acc[h] - mean*wsh[1024 + h]) * rstd;
        bias[(((b*16 + h)*1024 + q) << 10) | k] = f2b(bv);
    }
}

// ---------------------------------------------------------------------------
// Flash attention with pair bias + mask.  One block = (b, h, 64 q rows).
// 4 waves = 4 k-splits; each lane owns one q row; k-tiles of 32.
// Epilogue: multiply by precomputed sigmoid(g), store bf16 [2048,512].
// ---------------------------------------------------------------------------
__global__ __launch_bounds__(256) void attn_kernel(
    const bf16_t* __restrict__ qkvg,   // [2048][2048] q|k|v|sig(g)
    const bf16_t* __restrict__ bias,   // [2][16][1024][1024]
    const int* __restrict__ mask,      // [2][1024]
    bf16_t* __restrict__ outg)         // [2048][512]
{
    __shared__ float K_lds[4][1024];
    __shared__ float V_lds[4][1024];
    __shared__ float extra[4][2][64];
    int tid = threadIdx.x, lane = tid & 63, wave = tid >> 6;
    int blk = blockIdx.x;
    int qc = blk & 15, h = (blk >> 4) & 15, b = blk >> 8;
    int q = qc*64 + lane;
    int trow = b*1024 + q;

    float qreg[32];
    {
        const uint4* pq = (const uint4*)(qkvg + (size_t)trow*2048 + h*32);
        #pragma unroll
        for (int i = 0; i < 4; i++) {
            float f8[8]; unpack8(pq[i], f8);
            #pragma unroll
            for (int jj = 0; jj < 8; jj++) qreg[i*8 + jj] = f8[jj] * 0.17677669529663687f;
        }
    }
    float m_run = -1e30f, l_run = 0.f;
    float o[32];
    #pragma unroll
    for (int d = 0; d < 32; d++) o[d] = 0.f;
    const int* maskb = mask + b*1024;
    size_t bbase = ((size_t)(b*16 + h)*1024 + q) * 1024;

    for (int j = wave; j < 32; j += 4) {
        int k0 = j*32;
        // stage K,V tile (32 rows x 32 cols) into this wave's LDS region
        #pragma unroll
        for (int i = 0; i < 2; i++) {
            int cid = lane + i*64;
            int r = cid >> 2, sc8 = (cid & 3) << 3;
            size_t rowbase = (size_t)(b*1024 + k0 + r)*2048 + h*32 + sc8;
            uint4 ku = *(const uint4*)(qkvg + rowbase + 512);
            uint4 vu = *(const uint4*)(qkvg + rowbase + 1024);
            float kf[8], vf[8];
            unpack8(ku, kf); unpack8(vu, vf);
            int lb = r*32 + sc8;
            #pragma unroll
            for (int x = 0; x < 8; x++) { K_lds[wave][lb + x] = kf[x]; V_lds[wave][lb + x] = vf[x]; }
        }
        __syncthreads();
        // bias tile for this lane's q row
        float bv[32];
        {
            const uint4* pb = (const uint4*)(bias + bbase + k0);
            #pragma unroll
            for (int i = 0; i < 4; i++) { unpack8(pb[i], &bv[i*8]); }
        }
        float lg[32];
        float tmax = -1e30f;
        #pragma unroll
        for (int kk = 0; kk < 32; kk++) {
            float dot = 0.f;
            #pragma unroll
            for (int d = 0; d < 32; d++) dot = __builtin_fmaf(qreg[d], K_lds[wave][kk*32 + d], dot);
            float lgv = dot + bv[kk];
            bool ok = (maskb[k0 + kk] != 0);
            lgv = ok ? lgv : -1e30f;
            lg[kk] = lgv;
            tmax = fmaxf(tmax, lgv);
        }
        float m_new = fmaxf(m_run, tmax);
        float f = __expf(m_run - m_new);
        l_run *= f;
        #pragma unroll
        for (int d = 0; d < 32; d++) o[d] *= f;
        #pragma unroll
        for (int kk = 0; kk < 32; kk++) {
            float p = __expf(lg[kk] - m_new);
            p = (lg[kk] > -1e29f) ? p : 0.f;
            l_run += p;
            #pragma unroll
            for (int d = 0; d < 32; d++) o[d] = __builtin_fmaf(p, V_lds[wave][kk*32 + d], o[d]);
        }
        m_run = m_new;
        __syncthreads();
    }
    // write split partials: o[0..15]->K_lds, o[16..29]->V_lds, o[30..31]->extra
    #pragma unroll
    for (int d = 0; d < 16; d++) K_lds[wave][d*64 + lane] = o[d];
    #pragma unroll
    for (int d = 16; d < 30; d++) V_lds[wave][(d-16)*64 + lane] = o[d];
    extra[wave][0][lane] = o[30];
    extra[wave][1][lane] = o[31];
    V_lds[wave][896 + lane] = m_run;
    V_lds[wave][960 + lane] = l_run;
    __syncthreads();
    if (wave == 0) {
        int qi = lane;
        float M = -1e30f;
        #pragma unroll
        for (int i = 0; i < 4; i++) M = fmaxf(M, V_lds[i][896 + qi]);
        float L = 0.f;
        float od[32];
        #pragma unroll
        for (int d = 0; d < 32; d++) od[d] = 0.f;
        #pragma unroll
        for (int i = 0; i < 4; i++) {
            float mi = V_lds[i][896 + qi];
            float fi = __expf(mi - M);
            fi = (mi > -1e29f) ? fi : 0.f;
            L += V_lds[i][960 + qi] * fi;
            #pragma unroll
            for (int d = 0; d < 16; d++) od[d] += K_lds[i][d*64 + qi] * fi;
            #pragma unroll
            for (int d = 16; d < 30; d++) od[d] += V_lds[i][(d-16)*64 + qi] * fi;
            od[30] += extra[i][0][qi] * fi;
            od[31] += extra[i][1][qi] * fi;
        }
        float inv = 1.f / fmaxf(L, 1e-6f);
        const uint4* pg = (const uint4*)(qkvg + (size_t)trow*2048 + 1536 + h*32);
        bf16_t* po = outg + (size_t)trow*512 + h*32;
        #pragma unroll
        for (int i = 0; i < 4; i++) {
            float g8[8]; unpack8(pg[i], g8);
            #pragma unroll
            for (int jj = 0; jj < 8; jj++) po[i*8 + jj] = f2b(od[i*8 + jj] * inv * g8[jj]);
        }
    }
}

// ---------------------------------------------------------------------------
extern "C" void kernel_launch(void* const* d_in, const int* in_sizes, int n_in,
                              void* d_out, int out_size, void* d_ws, size_t ws_size,
                              hipStream_t stream)
{
    const float* a          = (const float*)d_in[0];
    const float* s          = (const float*)d_in[1];
    const float* z          = (const float*)d_in[2];
    const float* ln_s_scale = (const float*)d_in[3];
    const float* ada_w_s    = (const float*)d_in[4];
    const float* ada_b_s    = (const float*)d_in[5];
    const float* ada_w_nb   = (const float*)d_in[6];
    const float* wq         = (const float*)d_in[7];
    const float* bq         = (const float*)d_in[8];
    const float* wk         = (const float*)d_in[9];
    const float* bk         = (const float*)d_in[10];
    const float* wv         = (const float*)d_in[11];
    const float* bv_        = (const float*)d_in[12];
    const float* wg         = (const float*)d_in[13];
    const float* bg         = (const float*)d_in[14];
    const float* wo         = (const float*)d_in[15];
    const float* bo         = (const float*)d_in[16];
    const float* ln_z_scale = (const float*)d_in[17];
    const float* wz         = (const float*)d_in[18];
    const float* w_last     = (const float*)d_in[19];
    const float* b_last     = (const float*)d_in[20];
    const int*   maskp      = (const int*)d_in[21];
    float* out = (float*)d_out;
    char* ws = (char*)d_ws;

    bf16_t* Wada   = (bf16_t*)(ws + 0);
    bf16_t* Wlast  = (bf16_t*)(ws + 786432);
    bf16_t* Wqkvg  = (bf16_t*)(ws + 1179648);
    bf16_t* Wo     = (bf16_t*)(ws + 3276800);
    bf16_t* sbf    = (bf16_t*)(ws + 3801088);
    bf16_t* slnbf  = (bf16_t*)(ws + 5373952);
    float*  astats = (float*) (ws + 6946816);
    float*  wzs    = (float*) (ws + 6963200);
    float*  wsum   = (float*) (ws + 6967296);
    float*  bcat   = (float*) (ws + 6967552);
    float*  adaout = (float*) (ws + 6975744);
    bf16_t* anorm  = (bf16_t*)(ws + 15364352);
    bf16_t* qkvg   = (bf16_t*)(ws + 17461504);
    bf16_t* gate   = (bf16_t*)(ws + 25850112);
    bf16_t* attng  = (bf16_t*)(ws + 27947264);
    bf16_t* biasb  = (bf16_t*)(ws + 30044416);

    prep_kernel<<<dim3(768, 11), 256, 0, stream>>>(
        ada_w_s, ada_w_nb, w_last, wq, wk, wv, wg, wo, s, wz, ln_z_scale,
        bq, bk, bv_, bg, Wada, Wlast, Wqkvg, Wo, sbf, wzs, wsum, bcat);

    ln_kernel<<<2048, 256, 0, stream>>>(s, a, ln_s_scale, slnbf, astats);

    gemm_kernel<0><<<dim3(16, 32), 256, 0, stream>>>(
        slnbf, Wada, nullptr, 2048, 1024, 384, 0, nullptr, nullptr, adaout, nullptr);

    gemm_kernel<1><<<dim3(8, 32), 256, 0, stream>>>(
        sbf, Wlast, b_last, 2048, 512, 384, 0, nullptr, nullptr, nullptr, gate);

    anorm_kernel<<<1024, 256, 0, stream>>>(adaout, ada_b_s, a, astats, anorm);

    gemm_kernel<1><<<dim3(32, 32), 256, 0, stream>>>(
        anorm, Wqkvg, bcat, 2048, 2048, 512, 1536, nullptr, nullptr, nullptr, qkvg);

    biasz_kernel<<<16384, 128, 0, stream>>>(z, wzs, wsum, biasb);

    attn_kernel<<<512, 256, 0, stream>>>(qkvg, biasb, maskp, attng);

    gemm_kernel<2><<<dim3(8, 32), 256, 0, stream>>>(
        attng, Wo, bo, 2048, 512, 512, 0, gate, maskp, out, nullptr);

    (void)in_sizes; (void)n_in; (void)out_size; (void)ws_size;
}

// Round 2
// 829.658 us; speedup vs baseline: 1.3805x; 1.3805x over previous
//
#include <hip/hip_runtime.h>

typedef __bf16 bf16_t;
typedef bf16_t bf16x8 __attribute__((ext_vector_type(8)));
typedef float floatx4 __attribute__((ext_vector_type(4)));

#define NB 2
#define NL 1024
#define NCA 512
#define NCS 384
#define NCZ 64
#define NH 16
#define ND 32
#define NT (NB*NL)

#define QSCALE 0.17677669529663687f

static __device__ __forceinline__ bf16_t f2b(float f){ return (bf16_t)f; }
static __device__ __forceinline__ float sigmoidf_(float x){ return 1.f/(1.f + __expf(-x)); }

// ---------------------------------------------------------------------------
// prep: convert weights to bf16 (concatenated), build scaled wz + wsum + bcat
// wq/bq pre-scaled by 1/sqrt(D) so attention needs no scale.
// ---------------------------------------------------------------------------
__global__ __launch_bounds__(256) void prep_kernel(
    const float* __restrict__ aws, const float* __restrict__ awnb,
    const float* __restrict__ wlast,
    const float* __restrict__ wq, const float* __restrict__ wk,
    const float* __restrict__ wv, const float* __restrict__ wg,
    const float* __restrict__ wo, const float* __restrict__ s,
    const float* __restrict__ wz, const float* __restrict__ lnz,
    const float* __restrict__ pbq, const float* __restrict__ pbk,
    const float* __restrict__ pbv, const float* __restrict__ pbg,
    bf16_t* __restrict__ Wada, bf16_t* __restrict__ Wlast,
    bf16_t* __restrict__ Wqkvg, bf16_t* __restrict__ Wo, bf16_t* __restrict__ sbf,
    float* __restrict__ wzs, float* __restrict__ wsum, float* __restrict__ bcat)
{
    int seg = blockIdx.y, bx = blockIdx.x, tid = threadIdx.x;
    if (seg < 9) {
        const float* src; bf16_t* dst; int nelem; float scale = 1.f;
        switch (seg) {
            case 0: src=aws;  dst=Wada;          nelem=196608; break;
            case 1: src=awnb; dst=Wada+196608;   nelem=196608; break;
            case 2: src=wlast;dst=Wlast;         nelem=196608; break;
            case 3: src=wq;   dst=Wqkvg;         nelem=262144; scale=QSCALE; break;
            case 4: src=wk;   dst=Wqkvg+262144;  nelem=262144; break;
            case 5: src=wv;   dst=Wqkvg+524288;  nelem=262144; break;
            case 6: src=wg;   dst=Wqkvg+786432;  nelem=262144; break;
            case 7: src=wo;   dst=Wo;            nelem=262144; break;
            default: src=s;   dst=sbf;           nelem=786432; break;
        }
        int base = bx * 1024;
        if (base >= nelem) return;
        #pragma unroll
        for (int i = 0; i < 4; i++) {
            int e = base + tid + i*256;
            if (e < nelem) dst[e] = f2b(src[e] * scale);
        }
    } else if (seg == 9) {
        if (bx) return;
        #pragma unroll
        for (int i = 0; i < 4; i++) {
            int e = tid + i*256;           // 1024 = 16*64
            wzs[e] = wz[e] * lnz[e & 63];
        }
        __syncthreads();
        if (tid < 16) {
            float sum = 0.f;
            for (int c = 0; c < 64; c++) sum += wzs[tid*64 + c];
            wsum[tid] = sum;
        }
    } else {
        if (bx >= 2) return;
        #pragma unroll
        for (int i = 0; i < 4; i++) {
            int e = bx*1024 + tid + i*256;  // 2048
            float v = (e < 512) ? pbq[e]*QSCALE : (e < 1024) ? pbk[e-512]
                     : (e < 1536) ? pbv[e-1024] : pbg[e-1536];
            bcat[e] = v;
        }
    }
}

// ---------------------------------------------------------------------------
// LN of s (scaled, ->bf16) + mean/rstd stats of a.  One block per token.
// ---------------------------------------------------------------------------
__global__ __launch_bounds__(256) void ln_kernel(
    const float* __restrict__ s, const float* __restrict__ a,
    const float* __restrict__ lnscale,
    bf16_t* __restrict__ slnbf, float* __restrict__ astats)
{
    __shared__ float2 red[256];
    int t = blockIdx.x, tid = threadIdx.x;
    const float* sp = s + (size_t)t*NCS;
    float v0 = sp[tid];
    float v1 = (tid < 128) ? sp[256 + tid] : 0.f;
    float s1 = v0 + v1, s2 = v0*v0 + v1*v1;
    red[tid] = make_float2(s1, s2);
    __syncthreads();
    for (int off = 128; off; off >>= 1) {
        if (tid < off) { red[tid].x += red[tid+off].x; red[tid].y += red[tid+off].y; }
        __syncthreads();
    }
    float mean = red[0].x * (1.f/NCS);
    float var  = red[0].y * (1.f/NCS) - mean*mean;
    float rstd = rsqrtf(var + 1e-5f);
    slnbf[(size_t)t*NCS + tid] = f2b((v0 - mean)*rstd*lnscale[tid]);
    if (tid < 128) slnbf[(size_t)t*NCS + 256 + tid] = f2b((v1 - mean)*rstd*lnscale[256 + tid]);
    // a stats
    const float* ap = a + (size_t)t*NCA;
    float w0 = ap[tid], w1 = ap[256 + tid];
    float t1 = w0 + w1, t2 = w0*w0 + w1*w1;
    __syncthreads();
    red[tid] = make_float2(t1, t2);
    __syncthreads();
    for (int off = 128; off; off >>= 1) {
        if (tid < off) { red[tid].x += red[tid+off].x; red[tid].y += red[tid+off].y; }
        __syncthreads();
    }
    if (tid == 0) {
        float am = red[0].x * (1.f/NCA);
        float av = red[0].y * (1.f/NCA) - am*am;
        astats[2*t]   = am;
        astats[2*t+1] = rsqrtf(av + 1e-5f);
    }
}

// ---------------------------------------------------------------------------
// bf16 MFMA GEMM: C[M,N] = X[M,K] @ W[N,K]^T (+epilogue)
// MODE 0: store fp32 (no bias)
// MODE 1: +bias, sigmoid for n>=sig_start, store bf16
// MODE 2: +bias, *gate(bf16)[m,n], *mask[m], store fp32
// ---------------------------------------------------------------------------
template<int MODE>
__global__ __launch_bounds__(256) void gemm_kernel(
    const bf16_t* __restrict__ X, const bf16_t* __restrict__ W,
    const float* __restrict__ bias, int M, int N, int K, int sig_start,
    const bf16_t* __restrict__ gate, const int* __restrict__ mask,
    float* __restrict__ outF, bf16_t* __restrict__ outB)
{
    __shared__ __align__(16) bf16_t A_lds[64*40];
    __shared__ __align__(16) bf16_t B_lds[64*40];
    int tid = threadIdx.x;
    int lane = tid & 63, wave = tid >> 6;
    int l15 = lane & 15, quad = lane >> 4;
    int n0 = blockIdx.x * 64, m0 = blockIdx.y * 64;
    int lrow = tid >> 2, lchunk = tid & 3;
    const uint4* pX = (const uint4*)X;
    const uint4* pW = (const uint4*)W;
    floatx4 acc[4];
    #pragma unroll
    for (int i = 0; i < 4; i++) acc[i] = (floatx4){0.f,0.f,0.f,0.f};

    for (int k0 = 0; k0 < K; k0 += 32) {
        __syncthreads();
        *(uint4*)&A_lds[lrow*40 + lchunk*8] = pX[(((size_t)(m0+lrow))*K + k0 + lchunk*8) >> 3];
        *(uint4*)&B_lds[lrow*40 + lchunk*8] = pW[(((size_t)(n0+lrow))*K + k0 + lchunk*8) >> 3];
        __syncthreads();
        bf16x8 af = *(const bf16x8*)&A_lds[(wave*16 + l15)*40 + quad*8];
        #pragma unroll
        for (int ct = 0; ct < 4; ct++) {
            bf16x8 bfv = *(const bf16x8*)&B_lds[(ct*16 + l15)*40 + quad*8];
            acc[ct] = __builtin_amdgcn_mfma_f32_16x16x32_bf16(af, bfv, acc[ct], 0, 0, 0);
        }
    }
    #pragma unroll
    for (int ct = 0; ct < 4; ct++) {
        #pragma unroll
        for (int r = 0; r < 4; r++) {
            int m = m0 + wave*16 + quad*4 + r;
            int n = n0 + ct*16 + l15;
            float v = acc[ct][r];
            if (MODE == 0) {
                outF[(size_t)m*N + n] = v;
            } else if (MODE == 1) {
                v += bias[n];
                if (n >= sig_start) v = sigmoidf_(v);
                outB[(size_t)m*N + n] = f2b(v);
            } else {
                v += bias[n];
                v *= (float)gate[(size_t)m*N + n];
                v *= (mask[m] != 0) ? 1.f : 0.f;
                outF[(size_t)m*N + n] = v;
            }
        }
    }
}

// ---------------------------------------------------------------------------
// a_norm = sigmoid(ada_s + b) * (a-mean)*rstd + ada_nb   -> bf16
// ---------------------------------------------------------------------------
__global__ __launch_bounds__(256) void anorm_kernel(
    const float* __restrict__ ada_out, const float* __restrict__ ada_b,
    const float* __restrict__ a, const float* __restrict__ stats,
    bf16_t* __restrict__ anorm)
{
    int e = blockIdx.x * 1024 + threadIdx.x;
    #pragma unroll
    for (int i = 0; i < 4; i++, e += 256) {
        int t = e >> 9, c = e & 511;
        float x = ada_out[(size_t)t*1024 + c] + ada_b[c];
        float sig = sigmoidf_(x);
        float aln = (a[e] - stats[2*t]) * stats[2*t+1];
        anorm[e] = f2b(sig*aln + ada_out[(size_t)t*1024 + 512 + c]);
    }
}

// ---------------------------------------------------------------------------
// biasz v2 (MFMA): bias[b,h,q,k] = LN(z[b,q,k,:],lnz)@wz[h,:] + (mask[b,k]?0:-1e4)
// Per block: 128 consecutive (b,q,k) rows.  dot via mfma(z_bf16, wzs_bf16),
// LN correction applied algebraically: (dot - mean*wsum_h)*rstd.
// ---------------------------------------------------------------------------
__global__ __launch_bounds__(256) void biasz_kernel(
    const float* __restrict__ z, const float* __restrict__ wzs,
    const float* __restrict__ wsum, const int* __restrict__ mask,
    bf16_t* __restrict__ bias)
{
    __shared__ __align__(16) float  zf[128*68];       // z tile fp32, stride 68
    __shared__ __align__(16) float2 part[128*17];     // per-chunk partial (s1,s2)
    __shared__ __align__(16) bf16_t wzsbf[16*72];     // wzs bf16, stride 72
    __shared__ float wsumf[16];
    __shared__ float2 stats[128];                     // (mean, rstd)
    __shared__ float addm[128];                       // 0 or -10000 per local k
    __shared__ __align__(16) bf16_t outstage[16*136]; // [h][row], stride 136

    int tid = threadIdx.x;
    size_t row0 = (size_t)blockIdx.x * 128;
    int b  = (int)(row0 >> 20);
    int q  = (int)((row0 >> 10) & 1023);
    int k0 = (int)(row0 & 1023);

    // ---- Phase A: stage z (coalesced float4) + per-chunk partial stats
    {
        const float4* pz = (const float4*)(z + row0*64);
        int owner = tid & 15;          // chunk index within row (4 floats each)
        #pragma unroll
        for (int i = 0; i < 8; i++) {
            int idx = tid + i*256;
            float4 v = pz[idx];
            int row = idx >> 4;
            int ch  = owner * 4;
            zf[row*68 + ch]     = v.x;
            zf[row*68 + ch + 1] = v.y;
            zf[row*68 + ch + 2] = v.z;
            zf[row*68 + ch + 3] = v.w;
            float s1 = v.x + v.y + v.z + v.w;
            float s2 = v.x*v.x + v.y*v.y + v.z*v.z + v.w*v.w;
            part[row*17 + owner] = make_float2(s1, s2);
        }
    }
    __syncthreads();
    // ---- Phase B: stats per row (threads 0..127); stage wzs/wsum/mask (128..255)
    if (tid < 128) {
        float s1 = 0.f, s2 = 0.f;
        #pragma unroll
        for (int j = 0; j < 16; j++) {
            float2 p = part[tid*17 + j];
            s1 += p.x; s2 += p.y;
        }
        float mean = s1 * (1.f/64.f);
        float var  = s2 * (1.f/64.f) - mean*mean;
        stats[tid] = make_float2(mean, rsqrtf(var + 1e-5f));
        addm[tid] = (mask[b*1024 + k0 + tid] != 0) ? 0.f : -10000.f;
    } else {
        int t2 = tid - 128;
        #pragma unroll
        for (int i = 0; i < 8; i++) {
            int idx = t2*8 + i;           // 0..1023
            wzsbf[(idx >> 6)*72 + (idx & 63)] = f2b(wzs[idx]);
        }
        if (t2 < 16) wsumf[t2] = wsum[t2];
    }
    __syncthreads();
    // ---- Phase C: MFMA dot + LN correction; 4 waves x 2 m-tiles
    {
        int lane = tid & 63, wave = tid >> 6;
        int l15 = lane & 15, quad = lane >> 4;
        bf16x8 wf0, wf1;
        {
            wf0 = *(const bf16x8*)&wzsbf[l15*72 + quad*8];
            wf1 = *(const bf16x8*)&wzsbf[l15*72 + 32 + quad*8];
        }
        float wsum_n = wsumf[l15];
        #pragma unroll
        for (int mt = 0; mt < 2; mt++) {
            int m0 = wave*32 + mt*16;
            // A frags from fp32 LDS -> bf16
            const float* zrow = &zf[(m0 + l15)*68 + quad*8];
            bf16x8 za0, za1;
            {
                float4 f0 = *(const float4*)(zrow);
                float4 f1 = *(const float4*)(zrow + 4);
                float4 f2 = *(const float4*)(zrow + 32);
                float4 f3 = *(const float4*)(zrow + 36);
                za0 = (bf16x8){f2b(f0.x),f2b(f0.y),f2b(f0.z),f2b(f0.w),
                               f2b(f1.x),f2b(f1.y),f2b(f1.z),f2b(f1.w)};
                za1 = (bf16x8){f2b(f2.x),f2b(f2.y),f2b(f2.z),f2b(f2.w),
                               f2b(f3.x),f2b(f3.y),f2b(f3.z),f2b(f3.w)};
            }
            floatx4 acc = __builtin_amdgcn_mfma_f32_16x16x32_bf16(za0, wf0, (floatx4){0.f,0.f,0.f,0.f}, 0,0,0);
            acc = __builtin_amdgcn_mfma_f32_16x16x32_bf16(za1, wf1, acc, 0,0,0);
            #pragma unroll
            for (int r = 0; r < 4; r++) {
                int row = m0 + quad*4 + r;
                float2 st = stats[row];
                float bv = (acc[r] - st.x * wsum_n) * st.y + addm[row];
                outstage[l15*136 + row] = f2b(bv);
            }
        }
    }
    __syncthreads();
    // ---- Phase D: coalesced store  bias[b,h,q,k0+...]
    {
        int h = tid >> 4, seg = tid & 15;
        uint4 v = *(const uint4*)&outstage[h*136 + seg*8];
        size_t o = ((((size_t)(b*16 + h))*1024 + q) << 10) + k0 + seg*8;
        *(uint4*)&bias[o] = v;
    }
}

// ---------------------------------------------------------------------------
// MFMA flash attention.  Block = (b, h, 64 q rows); 4 waves x 16 q rows.
// K-tile = 64 keys.  QK^T: 4 mfma_16x16x32; PV: 4 mfma (P via LDS transpose,
// V staged transposed).  Mask already folded into bias.  Q pre-scaled.
// Epilogue: *sigmoid(g) (precomputed in qkvg), store bf16 [2048,512].
// ---------------------------------------------------------------------------
__global__ __launch_bounds__(256) void attn_kernel(
    const bf16_t* __restrict__ qkvg,   // [2048][2048] q|k|v|sig(g)
    const bf16_t* __restrict__ bias,   // [2][16][1024][1024] (mask folded)
    bf16_t* __restrict__ outg)         // [2048][512]
{
    __shared__ __align__(16) bf16_t K_lds[64*40];
    __shared__ __align__(16) bf16_t Vt_lds[32*72];
    __shared__ __align__(16) bf16_t P_lds[4][16*72];

    int tid = threadIdx.x, lane = tid & 63, wave = tid >> 6;
    int l15 = lane & 15, quad = lane >> 4;
    int blk = blockIdx.x;
    int qc = blk & 15, h = (blk >> 4) & 15, b = blk >> 8;
    int q0 = qc*64;

    // Q A-fragment (row = q0+wave*16+l15, k = quad*8+j), pre-scaled by 1/sqrt(D)
    bf16x8 qA = *(const bf16x8*)(qkvg + ((size_t)(b*1024 + q0 + wave*16 + l15))*2048 + h*32 + quad*8);

    floatx4 accO[2];
    accO[0] = (floatx4){0.f,0.f,0.f,0.f};
    accO[1] = (floatx4){0.f,0.f,0.f,0.f};
    float m_run[4], l_run[4];
    #pragma unroll
    for (int r = 0; r < 4; r++) { m_run[r] = -1e30f; l_run[r] = 0.f; }

    size_t biasrow[4];
    #pragma unroll
    for (int r = 0; r < 4; r++)
        biasrow[r] = (((size_t)(b*16 + h)*1024) + (q0 + wave*16 + quad*4 + r)) * 1024 + l15;

    const bf16_t* kvbase = qkvg + (size_t)b*1024*2048;
    int srow = tid >> 2, schunk = (tid & 3) << 3;

    for (int kt = 0; kt < 16; kt++) {
        int k0 = kt*64;
        // stage K [64 x 32] (stride 40) and V transposed [32 x 64] (stride 72)
        uint4 ku = *(const uint4*)(kvbase + (size_t)(k0 + srow)*2048 + 512 + h*32 + schunk);
        uint4 vu = *(const uint4*)(kvbase + (size_t)(k0 + srow)*2048 + 1024 + h*32 + schunk);
        *(uint4*)&K_lds[srow*40 + schunk] = ku;
        bf16_t vtmp[8]; *(uint4*)vtmp = vu;
        #pragma unroll
        for (int x = 0; x < 8; x++) Vt_lds[(schunk + x)*72 + srow] = vtmp[x];
        __syncthreads();

        // S = Q K^T  (C-layout: row=quad*4+r, col=ct*16+l15)
        floatx4 accS[4];
        #pragma unroll
        for (int ct = 0; ct < 4; ct++) {
            bf16x8 kf = *(const bf16x8*)&K_lds[(ct*16 + l15)*40 + quad*8];
            accS[ct] = __builtin_amdgcn_mfma_f32_16x16x32_bf16(qA, kf, (floatx4){0.f,0.f,0.f,0.f}, 0,0,0);
        }
        // + bias (mask folded in)
        float sv[4][4];
        #pragma unroll
        for (int r = 0; r < 4; r++) {
            const bf16_t* bp = bias + biasrow[r] + k0;
            #pragma unroll
            for (int ct = 0; ct < 4; ct++)
                sv[ct][r] = accS[ct][r] + (float)bp[ct*16];
        }
        // online softmax update
        float mnew[4], alpha[4];
        #pragma unroll
        for (int r = 0; r < 4; r++) {
            float tm = fmaxf(fmaxf(sv[0][r], sv[1][r]), fmaxf(sv[2][r], sv[3][r]));
            tm = fmaxf(tm, __shfl_xor(tm, 1));
            tm = fmaxf(tm, __shfl_xor(tm, 2));
            tm = fmaxf(tm, __shfl_xor(tm, 4));
            tm = fmaxf(tm, __shfl_xor(tm, 8));
            float mn = fmaxf(m_run[r], tm);
            mnew[r] = mn;
            alpha[r] = __expf(m_run[r] - mn);
            m_run[r] = mn;
        }
        #pragma unroll
        for (int r = 0; r < 4; r++) {
            float rs = 0.f;
            #pragma unroll
            for (int ct = 0; ct < 4; ct++) {
                float p = __expf(sv[ct][r] - mnew[r]);
                sv[ct][r] = p;
                rs += p;
            }
            rs += __shfl_xor(rs, 1); rs += __shfl_xor(rs, 2);
            rs += __shfl_xor(rs, 4); rs += __shfl_xor(rs, 8);
            l_run[r] = l_run[r]*alpha[r] + rs;
            accO[0][r] *= alpha[r];
            accO[1][r] *= alpha[r];
        }
        // P -> LDS (wave-private) in [qlocal][key] layout
        #pragma unroll
        for (int r = 0; r < 4; r++)
            #pragma unroll
            for (int ct = 0; ct < 4; ct++)
                P_lds[wave][(quad*4 + r)*72 + ct*16 + l15] = f2b(sv[ct][r]);
        // O += P V
        #pragma unroll
        for (int kk = 0; kk < 2; kk++) {
            bf16x8 pf = *(const bf16x8*)&P_lds[wave][l15*72 + kk*32 + quad*8];
            #pragma unroll
            for (int dh = 0; dh < 2; dh++) {
                bf16x8 vf = *(const bf16x8*)&Vt_lds[(dh*16 + l15)*72 + kk*32 + quad*8];
                accO[dh] = __builtin_amdgcn_mfma_f32_16x16x32_bf16(pf, vf, accO[dh], 0,0,0);
            }
        }
        __syncthreads();
    }
    // epilogue: /l, *sigmoid(g), store
    #pragma unroll
    for (int r = 0; r < 4; r++) {
        float inv = 1.f / fmaxf(l_run[r], 1e-6f);
        int trow = b*1024 + q0 + wave*16 + quad*4 + r;
        #pragma unroll
        for (int dh = 0; dh < 2; dh++) {
            float g = (float)qkvg[(size_t)trow*2048 + 1536 + h*32 + dh*16 + l15];
            outg[(size_t)trow*512 + h*32 + dh*16 + l15] = f2b(accO[dh][r]*inv*g);
        }
    }
}

// ---------------------------------------------------------------------------
extern "C" void kernel_launch(void* const* d_in, const int* in_sizes, int n_in,
                              void* d_out, int out_size, void* d_ws, size_t ws_size,
                              hipStream_t stream)
{
    const float* a          = (const float*)d_in[0];
    const float* s          = (const float*)d_in[1];
    const float* z          = (const float*)d_in[2];
    const float* ln_s_scale = (const float*)d_in[3];
    const float* ada_w_s    = (const float*)d_in[4];
    const float* ada_b_s    = (const float*)d_in[5];
    const float* ada_w_nb   = (const float*)d_in[6];
    const float* wq         = (const float*)d_in[7];
    const float* bq         = (const float*)d_in[8];
    const float* wk         = (const float*)d_in[9];
    const float* bk         = (const float*)d_in[10];
    const float* wv         = (const float*)d_in[11];
    const float* bv_        = (const float*)d_in[12];
    const float* wg         = (const float*)d_in[13];
    const float* bg         = (const float*)d_in[14];
    const float* wo         = (const float*)d_in[15];
    const float* bo         = (const float*)d_in[16];
    const float* ln_z_scale = (const float*)d_in[17];
    const float* wz         = (const float*)d_in[18];
    const float* w_last     = (const float*)d_in[19];
    const float* b_last     = (const float*)d_in[20];
    const int*   maskp      = (const int*)d_in[21];
    float* out = (float*)d_out;
    char* ws = (char*)d_ws;

    bf16_t* Wada   = (bf16_t*)(ws + 0);
    bf16_t* Wlast  = (bf16_t*)(ws + 786432);
    bf16_t* Wqkvg  = (bf16_t*)(ws + 1179648);
    bf16_t* Wo     = (bf16_t*)(ws + 3276800);
    bf16_t* sbf    = (bf16_t*)(ws + 3801088);
    bf16_t* slnbf  = (bf16_t*)(ws + 5373952);
    float*  astats = (float*) (ws + 6946816);
    float*  wzs    = (float*) (ws + 6963200);
    float*  wsum   = (float*) (ws + 6967296);
    float*  bcat   = (float*) (ws + 6967552);
    float*  adaout = (float*) (ws + 6975744);
    bf16_t* anorm  = (bf16_t*)(ws + 15364352);
    bf16_t* qkvg   = (bf16_t*)(ws + 17461504);
    bf16_t* gate   = (bf16_t*)(ws + 25850112);
    bf16_t* attng  = (bf16_t*)(ws + 27947264);
    bf16_t* biasb  = (bf16_t*)(ws + 30044416);

    prep_kernel<<<dim3(768, 11), 256, 0, stream>>>(
        ada_w_s, ada_w_nb, w_last, wq, wk, wv, wg, wo, s, wz, ln_z_scale,
        bq, bk, bv_, bg, Wada, Wlast, Wqkvg, Wo, sbf, wzs, wsum, bcat);

    ln_kernel<<<2048, 256, 0, stream>>>(s, a, ln_s_scale, slnbf, astats);

    gemm_kernel<0><<<dim3(16, 32), 256, 0, stream>>>(
        slnbf, Wada, nullptr, 2048, 1024, 384, 0, nullptr, nullptr, adaout, nullptr);

    gemm_kernel<1><<<dim3(8, 32), 256, 0, stream>>>(
        sbf, Wlast, b_last, 2048, 512, 384, 0, nullptr, nullptr, nullptr, gate);

    anorm_kernel<<<1024, 256, 0, stream>>>(adaout, ada_b_s, a, astats, anorm);

    gemm_kernel<1><<<dim3(32, 32), 256, 0, stream>>>(
        anorm, Wqkvg, bcat, 2048, 2048, 512, 1536, nullptr, nullptr, nullptr, qkvg);

    biasz_kernel<<<16384, 256, 0, stream>>>(z, wzs, wsum, maskp, biasb);

    attn_kernel<<<512, 256, 0, stream>>>(qkvg, biasb, attng);

    gemm_kernel<2><<<dim3(8, 32), 256, 0, stream>>>(
        attng, Wo, bo, 2048, 512, 512, 0, gate, maskp, out, nullptr);

    (void)in_sizes; (void)n_in; (void)out_size; (void)ws_size;
}